// Round 9
// baseline (5272.658 us; speedup 1.0000x reference)
//
#include <hip/hip_runtime.h>
#include <hip/hip_bf16.h>
#include <stdint.h>

// RNNPB via per-step MFMA GEMM (R9: W=4 x 4 row-tiles, halved LDS B-traffic).
// R8 postmortem: FETCH_SIZE is KB (~3MB one-time) -- no A-reload ever existed;
// A-frags live in AGPRs. Step is LDS-bound: 8 waves x 8 ds_read_b128 re-read
// the same 8.4KB Hx. W=4 halves that (32 reads ~550 cyc < matrix 621 cyc).
// Kept from R8: named frags, 3-ahead read/MFMA interleave, early d-tail,
// lgkm-only barrier. New: per-wave roles (w0/1 boundary, w2 d-tail, w3 out).
//   h_{t+1} = relu(M h_t + W1d d_{t+1} + cb' + W1p pb),  out_t = W2d h_t + b2d
// A (f16, 256x256): rows [0,240) h, [240,246) out (W2d); cols [0,240) M/W2d,
//   [240,246) W1d, 246 bias, 247/248 W1p, 249+ zero.
// B column n (Hx, stride 264 halves): [0,240) h_t | [240,246) d_{t+1} |
//   246=1.0 | 247=pb0 | 248=pb1 | 249..255 zero  -> 8 uniform b128 frags.
// 2 blocks x 16 batches; 4 waves x 4 row-tiles {w,w+4,w+8,w+12} x 8 K-frags.

#define T_STEPS 8192
#define HID     240
#define CTX     180
#define KTOT    256
#define HXROW   264                        // halves/row
#define HXBUF   (16*HXROW)                 // 4224 halves
#define A_HALVES (256*256)
#define SCRATCH_BYTES (A_HALVES*2 + 16)

typedef __hip_bfloat16 bf16;
typedef _Float16 f16;
typedef _Float16 half8  __attribute__((ext_vector_type(8)));
typedef _Float16 half4v __attribute__((ext_vector_type(4)));
typedef float    f32x4  __attribute__((ext_vector_type(4)));
typedef float    f32x2  __attribute__((ext_vector_type(2)));
typedef unsigned int uint4v __attribute__((ext_vector_type(4)));
typedef unsigned int uint2v __attribute__((ext_vector_type(2)));

#define MFMA16(A,B,C) __builtin_amdgcn_mfma_f32_16x16x32_f16((A),(B),(C),0,0,0)

__device__ __forceinline__ float ldin(const void* p, long i, bool f32) {
    return f32 ? ((const float*)p)[i] : __bfloat162float(((const bf16*)p)[i]);
}
__device__ __forceinline__ unsigned pkbf(float a, float b) {
    unsigned ua = (unsigned)__builtin_bit_cast(unsigned short, __float2bfloat16(a));
    unsigned ub = (unsigned)__builtin_bit_cast(unsigned short, __float2bfloat16(b));
    return ua | (ub << 16);
}
// LDS-ordering barrier WITHOUT vmem drain (out-stores/prefetch stay in flight)
__device__ __forceinline__ void barrier_lds() {
    asm volatile("s_waitcnt lgkmcnt(0)\n\ts_barrier" ::: "memory");
}

// fp32 arrays: low half-words are random mantissa (huge-as-bf16 w.p. ~0.45/word)
// or all-zero (bf16-grid). Real bf16 arrays: neither. (Verified R2-R8: bf16 path.)
__global__ __launch_bounds__(64) void detect_dtype(const void* data, int* flag) {
    unsigned int w  = ((const unsigned int*)data)[threadIdx.x];
    unsigned int lo = w & 0xFFFFu;
    unsigned int ex = (lo >> 7) & 0xFFu;
    unsigned long long huge = __ballot(ex >= 0x8Eu);
    unsigned long long zero = __ballot(lo == 0u);
    if (threadIdx.x == 0) *flag = (huge != 0ull || zero == ~0ull) ? 1 : 0;
}

// ---------------- build augmented A (f16) ----------------
__global__ __launch_bounds__(256) void build_A(
    const void* __restrict__ W1d, const void* __restrict__ b1d,
    const void* __restrict__ W1p, const void* __restrict__ b1p,
    const void* __restrict__ W1c, const void* __restrict__ b1c,
    const void* __restrict__ W2d, const void* __restrict__ b2d,
    const void* __restrict__ W2c, const void* __restrict__ b2c,
    f16* __restrict__ Aa, const int* __restrict__ flagp)
{
    const bool f32 = (*flagp != 0);
    int idx = blockIdx.x*256 + threadIdx.x;
    int r = idx >> 8, k = idx & 255;
    float v = 0.f;
    if (r < HID) {
        if (k < HID) {                           // M = W1c @ W2c
            float acc = 0.f;
            for (int c = 0; c < CTX; ++c)
                acc = fmaf(ldin(W1c, r*CTX+c, f32), ldin(W2c, c*HID+k, f32), acc);
            v = acc;
        } else if (k < 246) {                    // W1d columns
            v = ldin(W1d, r*6 + (k-240), f32);
        } else if (k == 246) {                   // bias: b1d+b1c+b1p + W1c@b2c
            float m0 = 0.f;
            for (int c = 0; c < CTX; ++c)
                m0 = fmaf(ldin(W1c, r*CTX+c, f32), ldin(b2c, c, f32), m0);
            v = ldin(b1d, r, f32) + ldin(b1c, r, f32) + ldin(b1p, r, f32) + m0;
        } else if (k <= 248) {                   // W1p columns
            v = ldin(W1p, r*2 + (k-247), f32);
        }
    } else if (r < 246) {                        // out rows
        int o = r - 240;
        if (k < HID)       v = ldin(W2d, o*HID + k, f32);
        else if (k == 246) v = ldin(b2d, o, f32);
    }
    Aa[idx] = (f16)v;
}

// ---------------- per-step MFMA recurrent kernel: 2 blocks x 16 batches ----------------
__global__ __launch_bounds__(256, 1) void rnn_mfma(
    const void* __restrict__ data,   // [30][6][8192]
    const void* __restrict__ b1d, const void* __restrict__ W1p,
    const void* __restrict__ b1p, const void* __restrict__ b1c,
    const void* __restrict__ W1d, const void* __restrict__ pb,
    const f16* __restrict__ Aa, const int* __restrict__ flagp,
    void* __restrict__ out)          // [30][8192][6]
{
    const bool f32 = (*flagp != 0);
    const int tid  = threadIdx.x;
    const int w    = tid >> 6;       // wave 0..3: tiles {w, w+4, w+8, w+12}; wave3 has 15
    const int l    = tid & 63;
    const int n16  = l & 15;
    const int quad = l >> 4;
    const int base = blockIdx.x * 16;
    const int bn   = base + n16;
    const bool bvalid = (bn < 30);

    __shared__ __align__(16) f16 Hx[2*HXBUF];        // 16,896 B
    __shared__ __align__(16) f16 dwin[2][32][16][8]; // 16,384 B

    // ---- zero Hx (rows >248 and pads must stay 0)
    {
        int* hz = (int*)Hx;
        for (int i = tid; i < HXBUF; i += 256) hz[i] = 0;    // 4224 ints = both buffers
    }
    __syncthreads();

    // ---- const rows 246/247/248 in both buffers
    if (tid < 32) {
        int bsel = tid >> 4, n = tid & 15;
        int nb = base + n; if (nb > 29) nb = 29;
        f16* col = Hx + bsel*HXBUF + n*HXROW;
        col[246] = (f16)1.0f;
        col[247] = (f16)ldin(pb, nb*2+0, f32);
        col[248] = (f16)ldin(pb, nb*2+1, f32);
    }

    // ---- h_0 = relu(cb + W1d d_0)  into Hx[0]
    for (int p = tid; p < HID*16; p += 256) {
        int n = p / HID, j = p - n*HID;
        int nb = base + n; if (nb > 29) nb = 29;
        float s = ldin(b1d, j, f32) + ldin(b1c, j, f32) + ldin(b1p, j, f32)
                + ldin(W1p, j*2+0, f32)*ldin(pb, nb*2+0, f32)
                + ldin(W1p, j*2+1, f32)*ldin(pb, nb*2+1, f32);
        for (int d = 0; d < 6; ++d)
            s = fmaf(ldin(W1d, j*6+d, f32), ldin(data, ((long)nb*6+d)*T_STEPS, f32), s);
        Hx[n*HXROW + j] = (f16)fmaxf(s, 0.f);
    }

    // ---- prefetch lane roles (tid<96 = waves 0-1): (pn, pd)
    const int pn = tid & 15, pd = tid >> 4;
    int pnb = base + pn; if (pnb > 29) pnb = 29;
    const long prow = ((long)pnb*6 + (pd < 6 ? pd : 0))*T_STEPS;

    // d_1 into Hx[0] rows 240..245
    if (tid < 96)
        Hx[pn*HXROW + 240 + pd] = (f16)ldin(data, prow + 1, f32);

    // dwin window 0: slot i <- g = 2+i
    if (tid < 96) {
        for (int i = 0; i < 32; ++i)
            dwin[0][i][pn][pd] = (f16)ldin(data, prow + 2 + i, f32);
    }

    // register span for window 1: halves [32,64) + dword pair [64,68)  (named vars)
    uint4v spA = {0,0,0,0}, spB = {0,0,0,0}, spC = {0,0,0,0}, spD = {0,0,0,0};
    uint2v spx = {0,0};
    if (tid < 96 && !f32) {
        const unsigned short* dp = (const unsigned short*)data + prow + 32;
        spA = ((const uint4v*)dp)[0];
        spB = ((const uint4v*)dp)[1];
        spC = ((const uint4v*)dp)[2];
        spD = ((const uint4v*)dp)[3];
        spx = *(const uint2v*)(dp + 32);
    }

    // ---- persistent A fragments: 32 NAMED half8 locals (tiles w, w+4, w+8, w+12)
    const f16* Ab0 = Aa + (size_t)((w +  0)*16 + n16)*KTOT + quad*8;
    const f16* Ab1 = Aa + (size_t)((w +  4)*16 + n16)*KTOT + quad*8;
    const f16* Ab2 = Aa + (size_t)((w +  8)*16 + n16)*KTOT + quad*8;
    const f16* Ab3 = Aa + (size_t)((w + 12)*16 + n16)*KTOT + quad*8;
    half8 a00 = *(const half8*)(Ab0 +   0), a01 = *(const half8*)(Ab0 +  32);
    half8 a02 = *(const half8*)(Ab0 +  64), a03 = *(const half8*)(Ab0 +  96);
    half8 a04 = *(const half8*)(Ab0 + 128), a05 = *(const half8*)(Ab0 + 160);
    half8 a06 = *(const half8*)(Ab0 + 192), a07 = *(const half8*)(Ab0 + 224);
    half8 a10 = *(const half8*)(Ab1 +   0), a11 = *(const half8*)(Ab1 +  32);
    half8 a12 = *(const half8*)(Ab1 +  64), a13 = *(const half8*)(Ab1 +  96);
    half8 a14 = *(const half8*)(Ab1 + 128), a15 = *(const half8*)(Ab1 + 160);
    half8 a16 = *(const half8*)(Ab1 + 192), a17 = *(const half8*)(Ab1 + 224);
    half8 a20 = *(const half8*)(Ab2 +   0), a21 = *(const half8*)(Ab2 +  32);
    half8 a22 = *(const half8*)(Ab2 +  64), a23 = *(const half8*)(Ab2 +  96);
    half8 a24 = *(const half8*)(Ab2 + 128), a25 = *(const half8*)(Ab2 + 160);
    half8 a26 = *(const half8*)(Ab2 + 192), a27 = *(const half8*)(Ab2 + 224);
    half8 a30 = *(const half8*)(Ab3 +   0), a31 = *(const half8*)(Ab3 +  32);
    half8 a32 = *(const half8*)(Ab3 +  64), a33 = *(const half8*)(Ab3 +  96);
    half8 a34 = *(const half8*)(Ab3 + 128), a35 = *(const half8*)(Ab3 + 160);
    half8 a36 = *(const half8*)(Ab3 + 192), a37 = *(const half8*)(Ab3 + 224);
    // drain A reads before any wave can store into the (possible) d_out-tail scratch
    asm volatile("s_waitcnt vmcnt(0)" ::: "memory");
    __syncthreads();

    const f16* hxread0 = Hx + n16*HXROW + quad*8;
    f16*       hxw     = Hx + n16*HXROW + quad*4;

    for (int t2 = 0; t2 < T_STEPS; t2 += 2) {
        #pragma unroll
        for (int s = 0; s < 2; ++s) {
            const int t = t2 + s;
            const int cur = s, nxt = s ^ 1;      // compile-time parity

            // ---- window boundary (waves 0-1): consume span -> dwin[b+1]; issue b+2
            if (s == 0 && (t & 31) == 0) {
                const int b = t >> 5;
                if (tid < 96) {
                    if (b <= 254) {
                        f16* dst = &dwin[(b+1)&1][0][pn][pd];  // slot stride 128 halves
                        if (!f32) {
                            // slots (2d-2, 2d-1) <- dword d of the 18-dword span
                            #define PUTD(dslot, dwval) do {                                   \
                                unsigned _dw = (dwval);                                       \
                                float _f0 = __builtin_bit_cast(float, (_dw & 0xFFFFu) << 16); \
                                float _f1 = __builtin_bit_cast(float, (_dw & 0xFFFF0000u));   \
                                dst[(2*(dslot)-2)*128] = (f16)_f0;                            \
                                dst[(2*(dslot)-1)*128] = (f16)_f1;                            \
                            } while (0)
                            PUTD( 1, spA.y); PUTD( 2, spA.z); PUTD( 3, spA.w);
                            PUTD( 4, spB.x); PUTD( 5, spB.y); PUTD( 6, spB.z); PUTD( 7, spB.w);
                            PUTD( 8, spC.x); PUTD( 9, spC.y); PUTD(10, spC.z); PUTD(11, spC.w);
                            PUTD(12, spD.x); PUTD(13, spD.y); PUTD(14, spD.z); PUTD(15, spD.w);
                            PUTD(16, spx.x);
                            #undef PUTD
                        } else {
                            for (int i = 0; i < 32; ++i) {
                                long g = 32*(long)(b+1) + 2 + i; if (g > 8191) g = 8191;
                                dst[i*128] = (f16)((const float*)data)[prow + g];
                            }
                        }
                    }
                    if (b <= 253 && !f32) {                    // span for window b+2
                        int A2 = 32*(b+2);                     // max 8160
                        const unsigned short* dp = (const unsigned short*)data + prow + A2;
                        spA = ((const uint4v*)dp)[0];
                        spB = ((const uint4v*)dp)[1];
                        spC = ((const uint4v*)dp)[2];
                        spD = ((const uint4v*)dp)[3];
                        long xo = A2 + 32; if (xo > 8188) xo = 8188;
                        spx = *(const uint2v*)((const unsigned short*)data + prow + xo);
                    }
                }
            }

            // ---- d-tail for step t+1 (wave 2): Hx[nxt] rows 240..245 <- d_{t+2}
            if (tid >= 128 && tid < 176) {
                int dl = tid - 128;
                int qn = dl & 15, pdw = dl >> 4;               // pdw 0..2
                unsigned dv = *(const unsigned*)&dwin[(t>>5)&1][t&31][qn][2*pdw];
                *(unsigned*)(Hx + nxt*HXBUF + qn*HXROW + 240 + 2*pdw) = dv;
            }

            // ---- B fragments (named, 3-ahead) + hand-unrolled MFMA (4 chains)
            const f16* hxc = hxread0 + cur*HXBUF;
            half8 b0 = *(const half8*)(hxc +   0);
            half8 b1 = *(const half8*)(hxc +  32);
            half8 b2 = *(const half8*)(hxc +  64);
            f32x4 c0 = {0.f,0.f,0.f,0.f}, c1 = {0.f,0.f,0.f,0.f};
            f32x4 c2 = {0.f,0.f,0.f,0.f}, c3 = {0.f,0.f,0.f,0.f};
            half8 b3 = *(const half8*)(hxc +  96);
            c0 = MFMA16(a00, b0, c0);  c1 = MFMA16(a10, b0, c1);
            c2 = MFMA16(a20, b0, c2);  c3 = MFMA16(a30, b0, c3);
            half8 b4 = *(const half8*)(hxc + 128);
            c0 = MFMA16(a01, b1, c0);  c1 = MFMA16(a11, b1, c1);
            c2 = MFMA16(a21, b1, c2);  c3 = MFMA16(a31, b1, c3);
            half8 b5 = *(const half8*)(hxc + 160);
            c0 = MFMA16(a02, b2, c0);  c1 = MFMA16(a12, b2, c1);
            c2 = MFMA16(a22, b2, c2);  c3 = MFMA16(a32, b2, c3);
            half8 b6 = *(const half8*)(hxc + 192);
            c0 = MFMA16(a03, b3, c0);  c1 = MFMA16(a13, b3, c1);
            c2 = MFMA16(a23, b3, c2);  c3 = MFMA16(a33, b3, c3);
            half8 b7 = *(const half8*)(hxc + 224);
            c0 = MFMA16(a04, b4, c0);  c1 = MFMA16(a14, b4, c1);
            c2 = MFMA16(a24, b4, c2);  c3 = MFMA16(a34, b4, c3);
            c0 = MFMA16(a05, b5, c0);  c1 = MFMA16(a15, b5, c1);
            c2 = MFMA16(a25, b5, c2);  c3 = MFMA16(a35, b5, c3);
            c0 = MFMA16(a06, b6, c0);  c1 = MFMA16(a16, b6, c1);
            c2 = MFMA16(a26, b6, c2);  c3 = MFMA16(a36, b6, c3);
            c0 = MFMA16(a07, b7, c0);  c1 = MFMA16(a17, b7, c1);
            c2 = MFMA16(a27, b7, c2);  c3 = MFMA16(a37, b7, c3);

            // ---- epilogue: h tiles -> relu -> Hx[nxt]; wave3 slot3 (tile15) -> out
            f16* hxn = hxw + nxt*HXBUF;
            #define HWRITE(CC, RT) do {                        \
                half4v hv;                                     \
                hv.x = (f16)fmaxf((CC).x, 0.f);                \
                hv.y = (f16)fmaxf((CC).y, 0.f);                \
                hv.z = (f16)fmaxf((CC).z, 0.f);                \
                hv.w = (f16)fmaxf((CC).w, 0.f);                \
                *(half4v*)(hxn + (RT)*16) = hv;                \
            } while (0)
            HWRITE(c0, w);
            HWRITE(c1, w + 4);
            HWRITE(c2, w + 8);
            if (w < 3) {
                HWRITE(c3, w + 12);
            } else if (bvalid) {                 // wave 3, tile 15: out rows 240..247
                long ob = ((long)bn*T_STEPS + t)*6;
                if (quad == 0) {                               // out elems 0..3
                    if (!f32) {
                        bf16* op = (bf16*)out + ob;
                        *(unsigned*)(op)     = pkbf(c3.x, c3.y);
                        *(unsigned*)(op + 2) = pkbf(c3.z, c3.w);
                    } else {
                        float* op = (float*)out + ob;
                        f32x2 p0 = {c3.x, c3.y}; *(f32x2*)(op)     = p0;
                        f32x2 p1 = {c3.z, c3.w}; *(f32x2*)(op + 2) = p1;
                    }
                } else if (quad == 1) {                        // out elems 4,5
                    if (!f32) {
                        bf16* op = (bf16*)out + ob;
                        *(unsigned*)(op + 4) = pkbf(c3.x, c3.y);
                    } else {
                        float* op = (float*)out + ob;
                        f32x2 p0 = {c3.x, c3.y}; *(f32x2*)(op + 4) = p0;
                    }
                }
            }
            #undef HWRITE
            barrier_lds();                       // lgkmcnt only -- vmem stays in flight
        }
    }
}

extern "C" void kernel_launch(void* const* d_in, const int* in_sizes, int n_in,
                              void* d_out, int out_size, void* d_ws, size_t ws_size,
                              hipStream_t stream) {
    const void* data = d_in[0];
    const void* W1d  = d_in[1];
    const void* b1d  = d_in[2];
    const void* W1p  = d_in[3];
    const void* b1p  = d_in[4];
    const void* W1c  = d_in[5];
    const void* b1c  = d_in[6];
    const void* W2d  = d_in[7];
    const void* b2d  = d_in[8];
    const void* W2c  = d_in[9];
    const void* b2c  = d_in[10];
    const void* pb   = d_in[11];

    size_t need = SCRATCH_BYTES;
    char* scratch;
    if (ws_size >= need) {
        scratch = (char*)d_ws;
    } else {
        size_t out_bytes = (size_t)30*T_STEPS*6*sizeof(bf16);
        scratch = (char*)d_out + ((out_bytes - need) & ~(size_t)255);
    }
    f16* Aa    = (f16*)scratch;
    int* flagp = (int*)(scratch + A_HALVES*2);

    detect_dtype<<<1, 64, 0, stream>>>(data, flagp);
    build_A<<<A_HALVES/256, 256, 0, stream>>>(W1d, b1d, W1p, b1p, W1c, b1c,
                                              W2d, b2d, W2c, b2c, Aa, flagp);
    rnn_mfma<<<2, 256, 0, stream>>>(data, b1d, W1p, b1p, b1c, W1d, pb,
                                    Aa, flagp, d_out);
}

// Round 10
// 4841.369 us; speedup vs baseline: 1.0891x; 1.0891x over previous
//
#include <hip/hip_runtime.h>
#include <hip/hip_bf16.h>
#include <stdint.h>

// RNNPB via per-step MFMA GEMM (R10 = R8 + overlap/skew shavings).
// Structural model (measured R8/R9): step is LDS-pipe-bound at W=8 --
// 64 ds_read_b128/CU/step (irreducible B ingest) ~= 1190 cyc floor vs
// matrix 621; W=4 regresses (serial chain exposed, R6/R9). Changes vs R8:
//   1. all 8 B-frag reads issued upfront (compiler lgkmcnt(N) interleave)
//   2. d-tail moved wave0 -> wave6 (balance barrier arrival skew)
//   h_{t+1} = relu(M h_t + W1d d_{t+1} + cb' + W1p pb),  out_t = W2d h_t + b2d
// A (f16, 256x256): rows [0,240) h, [240,246) out (W2d); cols [0,240) M/W2d,
//   [240,246) W1d, 246 bias, 247/248 W1p, 249+ zero.
// B column n (Hx, stride 264 halves): [0,240) h_t | [240,246) d_{t+1} |
//   246=1.0 | 247=pb0 | 248=pb1 | 249..255 zero  -> 8 uniform b128 frags.
// 2 blocks x 16 batches; 8 waves (2/SIMD) x 2 row-tiles x 8 K-frags.

#define T_STEPS 8192
#define HID     240
#define CTX     180
#define KTOT    256
#define HXROW   264                        // halves/row
#define HXBUF   (16*HXROW)                 // 4224 halves
#define A_HALVES (256*256)
#define SCRATCH_BYTES (A_HALVES*2 + 16)

typedef __hip_bfloat16 bf16;
typedef _Float16 f16;
typedef _Float16 half8  __attribute__((ext_vector_type(8)));
typedef _Float16 half4v __attribute__((ext_vector_type(4)));
typedef float    f32x4  __attribute__((ext_vector_type(4)));
typedef float    f32x2  __attribute__((ext_vector_type(2)));
typedef unsigned int uint4v __attribute__((ext_vector_type(4)));
typedef unsigned int uint2v __attribute__((ext_vector_type(2)));

#define MFMA16(A,B,C) __builtin_amdgcn_mfma_f32_16x16x32_f16((A),(B),(C),0,0,0)

__device__ __forceinline__ float ldin(const void* p, long i, bool f32) {
    return f32 ? ((const float*)p)[i] : __bfloat162float(((const bf16*)p)[i]);
}
__device__ __forceinline__ unsigned pkbf(float a, float b) {
    unsigned ua = (unsigned)__builtin_bit_cast(unsigned short, __float2bfloat16(a));
    unsigned ub = (unsigned)__builtin_bit_cast(unsigned short, __float2bfloat16(b));
    return ua | (ub << 16);
}
// LDS-ordering barrier WITHOUT vmem drain (out-stores/prefetch stay in flight)
__device__ __forceinline__ void barrier_lds() {
    asm volatile("s_waitcnt lgkmcnt(0)\n\ts_barrier" ::: "memory");
}

// fp32 arrays: low half-words are random mantissa (huge-as-bf16 w.p. ~0.45/word)
// or all-zero (bf16-grid). Real bf16 arrays: neither. (Verified R2-R9: bf16 path.)
__global__ __launch_bounds__(64) void detect_dtype(const void* data, int* flag) {
    unsigned int w  = ((const unsigned int*)data)[threadIdx.x];
    unsigned int lo = w & 0xFFFFu;
    unsigned int ex = (lo >> 7) & 0xFFu;
    unsigned long long huge = __ballot(ex >= 0x8Eu);
    unsigned long long zero = __ballot(lo == 0u);
    if (threadIdx.x == 0) *flag = (huge != 0ull || zero == ~0ull) ? 1 : 0;
}

// ---------------- build augmented A (f16) ----------------
__global__ __launch_bounds__(256) void build_A(
    const void* __restrict__ W1d, const void* __restrict__ b1d,
    const void* __restrict__ W1p, const void* __restrict__ b1p,
    const void* __restrict__ W1c, const void* __restrict__ b1c,
    const void* __restrict__ W2d, const void* __restrict__ b2d,
    const void* __restrict__ W2c, const void* __restrict__ b2c,
    f16* __restrict__ Aa, const int* __restrict__ flagp)
{
    const bool f32 = (*flagp != 0);
    int idx = blockIdx.x*256 + threadIdx.x;
    int r = idx >> 8, k = idx & 255;
    float v = 0.f;
    if (r < HID) {
        if (k < HID) {                           // M = W1c @ W2c
            float acc = 0.f;
            for (int c = 0; c < CTX; ++c)
                acc = fmaf(ldin(W1c, r*CTX+c, f32), ldin(W2c, c*HID+k, f32), acc);
            v = acc;
        } else if (k < 246) {                    // W1d columns
            v = ldin(W1d, r*6 + (k-240), f32);
        } else if (k == 246) {                   // bias: b1d+b1c+b1p + W1c@b2c
            float m0 = 0.f;
            for (int c = 0; c < CTX; ++c)
                m0 = fmaf(ldin(W1c, r*CTX+c, f32), ldin(b2c, c, f32), m0);
            v = ldin(b1d, r, f32) + ldin(b1c, r, f32) + ldin(b1p, r, f32) + m0;
        } else if (k <= 248) {                   // W1p columns
            v = ldin(W1p, r*2 + (k-247), f32);
        }
    } else if (r < 246) {                        // out rows
        int o = r - 240;
        if (k < HID)       v = ldin(W2d, o*HID + k, f32);
        else if (k == 246) v = ldin(b2d, o, f32);
    }
    Aa[idx] = (f16)v;
}

// ---------------- per-step MFMA recurrent kernel: 2 blocks x 16 batches ----------------
__global__ __launch_bounds__(512, 2) void rnn_mfma(
    const void* __restrict__ data,   // [30][6][8192]
    const void* __restrict__ b1d, const void* __restrict__ W1p,
    const void* __restrict__ b1p, const void* __restrict__ b1c,
    const void* __restrict__ W1d, const void* __restrict__ pb,
    const f16* __restrict__ Aa, const int* __restrict__ flagp,
    void* __restrict__ out)          // [30][8192][6]
{
    const bool f32 = (*flagp != 0);
    const int tid  = threadIdx.x;
    const int w    = tid >> 6;       // wave 0..7: row-tiles {2w, 2w+1}; wave7 tile15 = out
    const int l    = tid & 63;
    const int n16  = l & 15;
    const int quad = l >> 4;
    const int base = blockIdx.x * 16;
    const int bn   = base + n16;
    const bool bvalid = (bn < 30);

    __shared__ __align__(16) f16 Hx[2*HXBUF];        // 16,896 B
    __shared__ __align__(16) f16 dwin[2][32][16][8]; // 16,384 B

    // ---- zero Hx (rows >248 and pads must stay 0)
    {
        int* hz = (int*)Hx;
        for (int i = tid; i < HXBUF; i += 512) hz[i] = 0;    // 4224 ints = both buffers
    }
    __syncthreads();

    // ---- const rows 246/247/248 in both buffers
    if (tid < 32) {
        int bsel = tid >> 4, n = tid & 15;
        int nb = base + n; if (nb > 29) nb = 29;
        f16* col = Hx + bsel*HXBUF + n*HXROW;
        col[246] = (f16)1.0f;
        col[247] = (f16)ldin(pb, nb*2+0, f32);
        col[248] = (f16)ldin(pb, nb*2+1, f32);
    }

    // ---- h_0 = relu(cb + W1d d_0)  into Hx[0]
    for (int p = tid; p < HID*16; p += 512) {
        int n = p / HID, j = p - n*HID;
        int nb = base + n; if (nb > 29) nb = 29;
        float s = ldin(b1d, j, f32) + ldin(b1c, j, f32) + ldin(b1p, j, f32)
                + ldin(W1p, j*2+0, f32)*ldin(pb, nb*2+0, f32)
                + ldin(W1p, j*2+1, f32)*ldin(pb, nb*2+1, f32);
        for (int d = 0; d < 6; ++d)
            s = fmaf(ldin(W1d, j*6+d, f32), ldin(data, ((long)nb*6+d)*T_STEPS, f32), s);
        Hx[n*HXROW + j] = (f16)fmaxf(s, 0.f);
    }

    // ---- prefetch lane roles (tid<96 = waves 0-1): (pn, pd)
    const int pn = tid & 15, pd = tid >> 4;
    int pnb = base + pn; if (pnb > 29) pnb = 29;
    const long prow = ((long)pnb*6 + (pd < 6 ? pd : 0))*T_STEPS;

    // d_1 into Hx[0] rows 240..245
    if (tid < 96)
        Hx[pn*HXROW + 240 + pd] = (f16)ldin(data, prow + 1, f32);

    // dwin window 0: slot i <- g = 2+i
    if (tid < 96) {
        for (int i = 0; i < 32; ++i)
            dwin[0][i][pn][pd] = (f16)ldin(data, prow + 2 + i, f32);
    }

    // ---- d-tail lane roles (wave 6): (dn, dd2) covering 16 cols x 3 dword-pairs
    const int dl  = tid - 384;                   // valid when 0 <= dl < 48
    const int dn  = dl & 15, dd2 = (dl >> 4);    // dd2 0..2

    // register span for window 1: halves [32,64) + dword pair [64,68)  (named vars)
    uint4v spA = {0,0,0,0}, spB = {0,0,0,0}, spC = {0,0,0,0}, spD = {0,0,0,0};
    uint2v spx = {0,0};
    if (tid < 96 && !f32) {
        const unsigned short* dp = (const unsigned short*)data + prow + 32;
        spA = ((const uint4v*)dp)[0];
        spB = ((const uint4v*)dp)[1];
        spC = ((const uint4v*)dp)[2];
        spD = ((const uint4v*)dp)[3];
        spx = *(const uint2v*)(dp + 32);
    }

    // ---- persistent A fragments: 16 NAMED half8 locals (AGPR-resident)
    const f16* Ab0 = Aa + (size_t)((w*2+0)*16 + n16)*KTOT + quad*8;
    const f16* Ab1 = Aa + (size_t)((w*2+1)*16 + n16)*KTOT + quad*8;
    half8 a00 = *(const half8*)(Ab0 +   0), a01 = *(const half8*)(Ab0 +  32);
    half8 a02 = *(const half8*)(Ab0 +  64), a03 = *(const half8*)(Ab0 +  96);
    half8 a04 = *(const half8*)(Ab0 + 128), a05 = *(const half8*)(Ab0 + 160);
    half8 a06 = *(const half8*)(Ab0 + 192), a07 = *(const half8*)(Ab0 + 224);
    half8 a10 = *(const half8*)(Ab1 +   0), a11 = *(const half8*)(Ab1 +  32);
    half8 a12 = *(const half8*)(Ab1 +  64), a13 = *(const half8*)(Ab1 +  96);
    half8 a14 = *(const half8*)(Ab1 + 128), a15 = *(const half8*)(Ab1 + 160);
    half8 a16 = *(const half8*)(Ab1 + 192), a17 = *(const half8*)(Ab1 + 224);
    // drain A reads before any wave can store into the (possible) d_out-tail scratch
    asm volatile("s_waitcnt vmcnt(0)" ::: "memory");
    __syncthreads();

    const f16* hxread0 = Hx + n16*HXROW + quad*8;
    f16*       hxw     = Hx + n16*HXROW + quad*4;

    for (int t2 = 0; t2 < T_STEPS; t2 += 2) {
        #pragma unroll
        for (int s = 0; s < 2; ++s) {
            const int t = t2 + s;
            const int cur = s, nxt = s ^ 1;      // compile-time parity

            // ---- window boundary (waves 0-1): consume span -> dwin[b+1]; issue b+2
            if (s == 0 && (t & 31) == 0) {
                const int b = t >> 5;
                if (tid < 96) {
                    if (b <= 254) {
                        f16* dst = &dwin[(b+1)&1][0][pn][pd];  // slot stride 128 halves
                        if (!f32) {
                            // slots (2d-2, 2d-1) <- dword d of the 18-dword span
                            #define PUTD(dslot, dwval) do {                                   \
                                unsigned _dw = (dwval);                                       \
                                float _f0 = __builtin_bit_cast(float, (_dw & 0xFFFFu) << 16); \
                                float _f1 = __builtin_bit_cast(float, (_dw & 0xFFFF0000u));   \
                                dst[(2*(dslot)-2)*128] = (f16)_f0;                            \
                                dst[(2*(dslot)-1)*128] = (f16)_f1;                            \
                            } while (0)
                            PUTD( 1, spA.y); PUTD( 2, spA.z); PUTD( 3, spA.w);
                            PUTD( 4, spB.x); PUTD( 5, spB.y); PUTD( 6, spB.z); PUTD( 7, spB.w);
                            PUTD( 8, spC.x); PUTD( 9, spC.y); PUTD(10, spC.z); PUTD(11, spC.w);
                            PUTD(12, spD.x); PUTD(13, spD.y); PUTD(14, spD.z); PUTD(15, spD.w);
                            PUTD(16, spx.x);
                            #undef PUTD
                        } else {
                            for (int i = 0; i < 32; ++i) {
                                long g = 32*(long)(b+1) + 2 + i; if (g > 8191) g = 8191;
                                dst[i*128] = (f16)((const float*)data)[prow + g];
                            }
                        }
                    }
                    if (b <= 253 && !f32) {                    // span for window b+2
                        int A2 = 32*(b+2);                     // max 8160
                        const unsigned short* dp = (const unsigned short*)data + prow + A2;
                        spA = ((const uint4v*)dp)[0];
                        spB = ((const uint4v*)dp)[1];
                        spC = ((const uint4v*)dp)[2];
                        spD = ((const uint4v*)dp)[3];
                        long xo = A2 + 32; if (xo > 8188) xo = 8188;
                        spx = *(const uint2v*)((const unsigned short*)data + prow + xo);
                    }
                }
            }

            // ---- d-tail for step t+1 (wave 6): Hx[nxt] rows 240..245 <- d_{t+2}
            if (dl >= 0 && dl < 48) {
                unsigned dv = *(const unsigned*)&dwin[(t>>5)&1][t&31][dn][2*dd2];
                *(unsigned*)(Hx + nxt*HXBUF + dn*HXROW + 240 + 2*dd2) = dv;
            }

            // ---- B fragments: all 8 b128 reads issued upfront (compiler
            //      interleaves lgkmcnt(N) waits with the MFMA stream)
            const f16* hxc = hxread0 + cur*HXBUF;
            half8 b0 = *(const half8*)(hxc +   0);
            half8 b1 = *(const half8*)(hxc +  32);
            half8 b2 = *(const half8*)(hxc +  64);
            half8 b3 = *(const half8*)(hxc +  96);
            half8 b4 = *(const half8*)(hxc + 128);
            half8 b5 = *(const half8*)(hxc + 160);
            half8 b6 = *(const half8*)(hxc + 192);
            half8 b7 = *(const half8*)(hxc + 224);

            f32x4 c0 = {0.f,0.f,0.f,0.f}, c1 = {0.f,0.f,0.f,0.f};
            c0 = MFMA16(a00, b0, c0);  c1 = MFMA16(a10, b0, c1);
            c0 = MFMA16(a01, b1, c0);  c1 = MFMA16(a11, b1, c1);
            c0 = MFMA16(a02, b2, c0);  c1 = MFMA16(a12, b2, c1);
            c0 = MFMA16(a03, b3, c0);  c1 = MFMA16(a13, b3, c1);
            c0 = MFMA16(a04, b4, c0);  c1 = MFMA16(a14, b4, c1);
            c0 = MFMA16(a05, b5, c0);  c1 = MFMA16(a15, b5, c1);
            c0 = MFMA16(a06, b6, c0);  c1 = MFMA16(a16, b6, c1);
            c0 = MFMA16(a07, b7, c0);  c1 = MFMA16(a17, b7, c1);

            // ---- epilogue: h rows -> relu -> Hx[nxt]; out rows (wave 7) -> global
            f16* hxn = hxw + nxt*HXBUF;
            {   // tile 2w (always an h-tile: 2w <= 14)
                half4v hv;
                hv.x = (f16)fmaxf(c0.x, 0.f);
                hv.y = (f16)fmaxf(c0.y, 0.f);
                hv.z = (f16)fmaxf(c0.z, 0.f);
                hv.w = (f16)fmaxf(c0.w, 0.f);
                *(half4v*)(hxn + (2*w)*16) = hv;
            }
            if (w < 7) {                         // tile 2w+1: h-tile
                half4v hv;
                hv.x = (f16)fmaxf(c1.x, 0.f);
                hv.y = (f16)fmaxf(c1.y, 0.f);
                hv.z = (f16)fmaxf(c1.z, 0.f);
                hv.w = (f16)fmaxf(c1.w, 0.f);
                *(half4v*)(hxn + (2*w+1)*16) = hv;
            } else if (bvalid) {                 // wave 7, tile 15: out rows 240..247
                long ob = ((long)bn*T_STEPS + t)*6;
                if (quad == 0) {                               // out elems 0..3
                    if (!f32) {
                        bf16* op = (bf16*)out + ob;
                        *(unsigned*)(op)     = pkbf(c1.x, c1.y);
                        *(unsigned*)(op + 2) = pkbf(c1.z, c1.w);
                    } else {
                        float* op = (float*)out + ob;
                        f32x2 p0 = {c1.x, c1.y}; *(f32x2*)(op)     = p0;
                        f32x2 p1 = {c1.z, c1.w}; *(f32x2*)(op + 2) = p1;
                    }
                } else if (quad == 1) {                        // out elems 4,5
                    if (!f32) {
                        bf16* op = (bf16*)out + ob;
                        *(unsigned*)(op + 4) = pkbf(c1.x, c1.y);
                    } else {
                        float* op = (float*)out + ob;
                        f32x2 p0 = {c1.x, c1.y}; *(f32x2*)(op + 4) = p0;
                    }
                }
            }
            barrier_lds();                       // lgkmcnt only -- vmem stays in flight
        }
    }
}

extern "C" void kernel_launch(void* const* d_in, const int* in_sizes, int n_in,
                              void* d_out, int out_size, void* d_ws, size_t ws_size,
                              hipStream_t stream) {
    const void* data = d_in[0];
    const void* W1d  = d_in[1];
    const void* b1d  = d_in[2];
    const void* W1p  = d_in[3];
    const void* b1p  = d_in[4];
    const void* W1c  = d_in[5];
    const void* b1c  = d_in[6];
    const void* W2d  = d_in[7];
    const void* b2d  = d_in[8];
    const void* W2c  = d_in[9];
    const void* b2c  = d_in[10];
    const void* pb   = d_in[11];

    size_t need = SCRATCH_BYTES;
    char* scratch;
    if (ws_size >= need) {
        scratch = (char*)d_ws;
    } else {
        size_t out_bytes = (size_t)30*T_STEPS*6*sizeof(bf16);
        scratch = (char*)d_out + ((out_bytes - need) & ~(size_t)255);
    }
    f16* Aa    = (f16*)scratch;
    int* flagp = (int*)(scratch + A_HALVES*2);

    detect_dtype<<<1, 64, 0, stream>>>(data, flagp);
    build_A<<<A_HALVES/256, 256, 0, stream>>>(W1d, b1d, W1p, b1p, W1c, b1c,
                                              W2d, b2d, W2c, b2c, Aa, flagp);
    rnn_mfma<<<2, 512, 0, stream>>>(data, b1d, W1p, b1p, b1c, W1d, pb,
                                    Aa, flagp, d_out);
}

// Round 11
// 3894.279 us; speedup vs baseline: 1.3539x; 1.2432x over previous
//
#include <hip/hip_runtime.h>
#include <hip/hip_bf16.h>
#include <stdint.h>

// RNNPB via per-step MFMA GEMM (R11 = R8 minus the dwin subsystem).
// The d-input (6 rows x 16 cols/step) is fed by a 96-lane register FIFO:
// each step, waves 0-1 issue one 2B global load (d[t+4], L2-hot, consumed
// 2 steps later) and write d[t+2] into Hx[nxt] rows 240..245 (1 cvt + b16).
// Removes: 16KB dwin LDS, 32-step boundary bursts (17 loads + 64 cvt + 32
// LDS writes on waves 0-1), per-step d-tail LDS reads/writes + conflicts.
//   h_{t+1} = relu(M h_t + W1d d_{t+1} + cb' + W1p pb),  out_t = W2d h_t + b2d
// A (f16, 256x256): rows [0,240) h, [240,246) out (W2d); cols [0,240) M/W2d,
//   [240,246) W1d, 246 bias, 247/248 W1p, 249+ zero.
// B column n (Hx, stride 264 halves): [0,240) h_t | [240,246) d_{t+1} |
//   246=1.0 | 247=pb0 | 248=pb1 | 249..255 zero  -> 8 uniform b128 frags.
// 2 blocks x 16 batches; 8 waves (2/SIMD) x 2 row-tiles x 8 K-frags.

#define T_STEPS 8192
#define HID     240
#define CTX     180
#define KTOT    256
#define HXROW   264                        // halves/row (33 x 16B: odd superbank stride)
#define HXBUF   (16*HXROW)                 // 4224 halves
#define A_HALVES (256*256)
#define SCRATCH_BYTES (A_HALVES*2 + 16)

typedef __hip_bfloat16 bf16;
typedef _Float16 f16;
typedef _Float16 half8  __attribute__((ext_vector_type(8)));
typedef _Float16 half4v __attribute__((ext_vector_type(4)));
typedef float    f32x4  __attribute__((ext_vector_type(4)));
typedef float    f32x2  __attribute__((ext_vector_type(2)));

#define MFMA16(A,B,C) __builtin_amdgcn_mfma_f32_16x16x32_f16((A),(B),(C),0,0,0)

__device__ __forceinline__ float ldin(const void* p, long i, bool f32) {
    return f32 ? ((const float*)p)[i] : __bfloat162float(((const bf16*)p)[i]);
}
__device__ __forceinline__ unsigned pkbf(float a, float b) {
    unsigned ua = (unsigned)__builtin_bit_cast(unsigned short, __float2bfloat16(a));
    unsigned ub = (unsigned)__builtin_bit_cast(unsigned short, __float2bfloat16(b));
    return ua | (ub << 16);
}
// LDS-ordering barrier WITHOUT vmem drain (out-stores/d-loads stay in flight)
__device__ __forceinline__ void barrier_lds() {
    asm volatile("s_waitcnt lgkmcnt(0)\n\ts_barrier" ::: "memory");
}

// fp32 arrays: low half-words are random mantissa (huge-as-bf16 w.p. ~0.45/word)
// or all-zero (bf16-grid). Real bf16 arrays: neither. (Verified R2-R10: bf16 path.)
__global__ __launch_bounds__(64) void detect_dtype(const void* data, int* flag) {
    unsigned int w  = ((const unsigned int*)data)[threadIdx.x];
    unsigned int lo = w & 0xFFFFu;
    unsigned int ex = (lo >> 7) & 0xFFu;
    unsigned long long huge = __ballot(ex >= 0x8Eu);
    unsigned long long zero = __ballot(lo == 0u);
    if (threadIdx.x == 0) *flag = (huge != 0ull || zero == ~0ull) ? 1 : 0;
}

// ---------------- build augmented A (f16) ----------------
__global__ __launch_bounds__(256) void build_A(
    const void* __restrict__ W1d, const void* __restrict__ b1d,
    const void* __restrict__ W1p, const void* __restrict__ b1p,
    const void* __restrict__ W1c, const void* __restrict__ b1c,
    const void* __restrict__ W2d, const void* __restrict__ b2d,
    const void* __restrict__ W2c, const void* __restrict__ b2c,
    f16* __restrict__ Aa, const int* __restrict__ flagp)
{
    const bool f32 = (*flagp != 0);
    int idx = blockIdx.x*256 + threadIdx.x;
    int r = idx >> 8, k = idx & 255;
    float v = 0.f;
    if (r < HID) {
        if (k < HID) {                           // M = W1c @ W2c
            float acc = 0.f;
            for (int c = 0; c < CTX; ++c)
                acc = fmaf(ldin(W1c, r*CTX+c, f32), ldin(W2c, c*HID+k, f32), acc);
            v = acc;
        } else if (k < 246) {                    // W1d columns
            v = ldin(W1d, r*6 + (k-240), f32);
        } else if (k == 246) {                   // bias: b1d+b1c+b1p + W1c@b2c
            float m0 = 0.f;
            for (int c = 0; c < CTX; ++c)
                m0 = fmaf(ldin(W1c, r*CTX+c, f32), ldin(b2c, c, f32), m0);
            v = ldin(b1d, r, f32) + ldin(b1c, r, f32) + ldin(b1p, r, f32) + m0;
        } else if (k <= 248) {                   // W1p columns
            v = ldin(W1p, r*2 + (k-247), f32);
        }
    } else if (r < 246) {                        // out rows
        int o = r - 240;
        if (k < HID)       v = ldin(W2d, o*HID + k, f32);
        else if (k == 246) v = ldin(b2d, o, f32);
    }
    Aa[idx] = (f16)v;
}

// ---------------- per-step MFMA recurrent kernel: 2 blocks x 16 batches ----------------
__global__ __launch_bounds__(512, 2) void rnn_mfma(
    const void* __restrict__ data,   // [30][6][8192]
    const void* __restrict__ b1d, const void* __restrict__ W1p,
    const void* __restrict__ b1p, const void* __restrict__ b1c,
    const void* __restrict__ W1d, const void* __restrict__ pb,
    const f16* __restrict__ Aa, const int* __restrict__ flagp,
    void* __restrict__ out)          // [30][8192][6]
{
    const bool f32 = (*flagp != 0);
    const int tid  = threadIdx.x;
    const int w    = tid >> 6;       // wave 0..7: row-tiles {2w, 2w+1}; wave7 tile15 = out
    const int l    = tid & 63;
    const int n16  = l & 15;
    const int quad = l >> 4;
    const int base = blockIdx.x * 16;
    const int bn   = base + n16;
    const bool bvalid = (bn < 30);

    __shared__ __align__(16) f16 Hx[2*HXBUF];        // 16,896 B (only LDS left)

    // ---- zero Hx (rows >248 and pads must stay 0)
    {
        int* hz = (int*)Hx;
        for (int i = tid; i < HXBUF; i += 512) hz[i] = 0;    // 4224 ints = both buffers
    }
    __syncthreads();

    // ---- const rows 246/247/248 in both buffers
    if (tid < 32) {
        int bsel = tid >> 4, n = tid & 15;
        int nb = base + n; if (nb > 29) nb = 29;
        f16* col = Hx + bsel*HXBUF + n*HXROW;
        col[246] = (f16)1.0f;
        col[247] = (f16)ldin(pb, nb*2+0, f32);
        col[248] = (f16)ldin(pb, nb*2+1, f32);
    }

    // ---- h_0 = relu(cb + W1d d_0)  into Hx[0]
    for (int p = tid; p < HID*16; p += 512) {
        int n = p / HID, j = p - n*HID;
        int nb = base + n; if (nb > 29) nb = 29;
        float s = ldin(b1d, j, f32) + ldin(b1c, j, f32) + ldin(b1p, j, f32)
                + ldin(W1p, j*2+0, f32)*ldin(pb, nb*2+0, f32)
                + ldin(W1p, j*2+1, f32)*ldin(pb, nb*2+1, f32);
        for (int d = 0; d < 6; ++d)
            s = fmaf(ldin(W1d, j*6+d, f32), ldin(data, ((long)nb*6+d)*T_STEPS, f32), s);
        Hx[n*HXROW + j] = (f16)fmaxf(s, 0.f);
    }

    // ---- d-feed lane roles (tid<96 = waves 0-1): (pn, pd)
    const int pn = tid & 15, pd = tid >> 4;
    int pnb = base + pn; if (pnb > 29) pnb = 29;
    const long prow = ((long)pnb*6 + (pd < 6 ? pd : 0))*T_STEPS;

    // d_1 into Hx[0] rows 240..245
    if (tid < 96)
        Hx[pn*HXROW + 240 + pd] = (f16)ldin(data, prow + 1, f32);

    // d-FIFO preload: u0 = raw d[2] (consumed step 0), u1 = raw d[3] (step 1)
    unsigned u0 = 0, u1 = 0;
    if (tid < 96) {
        if (!f32) {
            u0 = ((const unsigned short*)data)[prow + 2];
            u1 = ((const unsigned short*)data)[prow + 3];
        } else {
            u0 = __builtin_bit_cast(unsigned, ((const float*)data)[prow + 2]);
            u1 = __builtin_bit_cast(unsigned, ((const float*)data)[prow + 3]);
        }
    }

    // ---- persistent A fragments: 16 NAMED half8 locals (AGPR-resident)
    const f16* Ab0 = Aa + (size_t)((w*2+0)*16 + n16)*KTOT + quad*8;
    const f16* Ab1 = Aa + (size_t)((w*2+1)*16 + n16)*KTOT + quad*8;
    half8 a00 = *(const half8*)(Ab0 +   0), a01 = *(const half8*)(Ab0 +  32);
    half8 a02 = *(const half8*)(Ab0 +  64), a03 = *(const half8*)(Ab0 +  96);
    half8 a04 = *(const half8*)(Ab0 + 128), a05 = *(const half8*)(Ab0 + 160);
    half8 a06 = *(const half8*)(Ab0 + 192), a07 = *(const half8*)(Ab0 + 224);
    half8 a10 = *(const half8*)(Ab1 +   0), a11 = *(const half8*)(Ab1 +  32);
    half8 a12 = *(const half8*)(Ab1 +  64), a13 = *(const half8*)(Ab1 +  96);
    half8 a14 = *(const half8*)(Ab1 + 128), a15 = *(const half8*)(Ab1 + 160);
    half8 a16 = *(const half8*)(Ab1 + 192), a17 = *(const half8*)(Ab1 + 224);
    // drain A reads before any wave can store into the (possible) d_out-tail scratch
    asm volatile("s_waitcnt vmcnt(0)" ::: "memory");
    __syncthreads();

    const f16* hxread0 = Hx + n16*HXROW + quad*8;
    f16*       hxw     = Hx + n16*HXROW + quad*4;

    for (int t2 = 0; t2 < T_STEPS; t2 += 2) {
        #pragma unroll
        for (int s = 0; s < 2; ++s) {
            const int t = t2 + s;
            const int cur = s, nxt = s ^ 1;      // compile-time parity

            // ---- d-feed (waves 0-1): write d_{t+2} -> Hx[nxt]; issue load d[t+4]
            if (tid < 96) {
                unsigned uc = (s == 0) ? u0 : u1;
                float dv = f32 ? __builtin_bit_cast(float, uc)
                               : __builtin_bit_cast(float, uc << 16);
                Hx[nxt*HXBUF + pn*HXROW + 240 + pd] = (f16)dv;
                long g = t + 4; if (g > T_STEPS-1) g = T_STEPS-1;
                unsigned un;
                if (!f32) un = ((const unsigned short*)data)[prow + g];
                else      un = __builtin_bit_cast(unsigned, ((const float*)data)[prow + g]);
                if (s == 0) u0 = un; else u1 = un;
            }

            // ---- B fragments (named, 3-ahead) + hand-unrolled MFMA (R8 pattern)
            const f16* hxc = hxread0 + cur*HXBUF;
            half8 b0 = *(const half8*)(hxc +   0);
            half8 b1 = *(const half8*)(hxc +  32);
            half8 b2 = *(const half8*)(hxc +  64);
            f32x4 c0 = {0.f,0.f,0.f,0.f}, c1 = {0.f,0.f,0.f,0.f};
            half8 b3 = *(const half8*)(hxc +  96);
            c0 = MFMA16(a00, b0, c0);  c1 = MFMA16(a10, b0, c1);
            half8 b4 = *(const half8*)(hxc + 128);
            c0 = MFMA16(a01, b1, c0);  c1 = MFMA16(a11, b1, c1);
            half8 b5 = *(const half8*)(hxc + 160);
            c0 = MFMA16(a02, b2, c0);  c1 = MFMA16(a12, b2, c1);
            half8 b6 = *(const half8*)(hxc + 192);
            c0 = MFMA16(a03, b3, c0);  c1 = MFMA16(a13, b3, c1);
            half8 b7 = *(const half8*)(hxc + 224);
            c0 = MFMA16(a04, b4, c0);  c1 = MFMA16(a14, b4, c1);
            c0 = MFMA16(a05, b5, c0);  c1 = MFMA16(a15, b5, c1);
            c0 = MFMA16(a06, b6, c0);  c1 = MFMA16(a16, b6, c1);
            c0 = MFMA16(a07, b7, c0);  c1 = MFMA16(a17, b7, c1);

            // ---- epilogue: h rows -> relu -> Hx[nxt]; out rows (wave 7) -> global
            f16* hxn = hxw + nxt*HXBUF;
            {   // tile 2w (always an h-tile: 2w <= 14)
                half4v hv;
                hv.x = (f16)fmaxf(c0.x, 0.f);
                hv.y = (f16)fmaxf(c0.y, 0.f);
                hv.z = (f16)fmaxf(c0.z, 0.f);
                hv.w = (f16)fmaxf(c0.w, 0.f);
                *(half4v*)(hxn + (2*w)*16) = hv;
            }
            if (w < 7) {                         // tile 2w+1: h-tile
                half4v hv;
                hv.x = (f16)fmaxf(c1.x, 0.f);
                hv.y = (f16)fmaxf(c1.y, 0.f);
                hv.z = (f16)fmaxf(c1.z, 0.f);
                hv.w = (f16)fmaxf(c1.w, 0.f);
                *(half4v*)(hxn + (2*w+1)*16) = hv;
            } else if (bvalid) {                 // wave 7, tile 15: out rows 240..247
                long ob = ((long)bn*T_STEPS + t)*6;
                if (quad == 0) {                               // out elems 0..3
                    if (!f32) {
                        bf16* op = (bf16*)out + ob;
                        *(unsigned*)(op)     = pkbf(c1.x, c1.y);
                        *(unsigned*)(op + 2) = pkbf(c1.z, c1.w);
                    } else {
                        float* op = (float*)out + ob;
                        f32x2 p0 = {c1.x, c1.y}; *(f32x2*)(op)     = p0;
                        f32x2 p1 = {c1.z, c1.w}; *(f32x2*)(op + 2) = p1;
                    }
                } else if (quad == 1) {                        // out elems 4,5
                    if (!f32) {
                        bf16* op = (bf16*)out + ob;
                        *(unsigned*)(op + 4) = pkbf(c1.x, c1.y);
                    } else {
                        float* op = (float*)out + ob;
                        f32x2 p0 = {c1.x, c1.y}; *(f32x2*)(op + 4) = p0;
                    }
                }
            }
            barrier_lds();                       // lgkmcnt only -- vmem stays in flight
        }
    }
}

extern "C" void kernel_launch(void* const* d_in, const int* in_sizes, int n_in,
                              void* d_out, int out_size, void* d_ws, size_t ws_size,
                              hipStream_t stream) {
    const void* data = d_in[0];
    const void* W1d  = d_in[1];
    const void* b1d  = d_in[2];
    const void* W1p  = d_in[3];
    const void* b1p  = d_in[4];
    const void* W1c  = d_in[5];
    const void* b1c  = d_in[6];
    const void* W2d  = d_in[7];
    const void* b2d  = d_in[8];
    const void* W2c  = d_in[9];
    const void* b2c  = d_in[10];
    const void* pb   = d_in[11];

    size_t need = SCRATCH_BYTES;
    char* scratch;
    if (ws_size >= need) {
        scratch = (char*)d_ws;
    } else {
        size_t out_bytes = (size_t)30*T_STEPS*6*sizeof(bf16);
        scratch = (char*)d_out + ((out_bytes - need) & ~(size_t)255);
    }
    f16* Aa    = (f16*)scratch;
    int* flagp = (int*)(scratch + A_HALVES*2);

    detect_dtype<<<1, 64, 0, stream>>>(data, flagp);
    build_A<<<A_HALVES/256, 256, 0, stream>>>(W1d, b1d, W1p, b1p, W1c, b1c,
                                              W2d, b2d, W2c, b2c, Aa, flagp);
    rnn_mfma<<<2, 512, 0, stream>>>(data, b1d, W1p, b1p, b1c, W1d, pb,
                                    Aa, flagp, d_out);
}